// Round 5
// baseline (645.377 us; speedup 1.0000x reference)
//
#include <hip/hip_runtime.h>
#include <math.h>

#define D_ 128
#define H_ 160
#define W_ 160
#define NVOX (D_*H_*W_)
#define HW (H_*W_)
#define N4 (NVOX/4)
#define HW4 (HW/4)

// Gaussian kernel, sigma=1, radius=2, normalized
#define K0 0.40261996f
#define K1 0.24420134f
#define K2 0.05448868f

union F4 { float4 v; float a[4]; };

__device__ __forceinline__ float4 zero4() { float4 z; z.x=z.y=z.z=z.w=0.f; return z; }
__device__ __forceinline__ float4 bcast4(float x) { float4 r; r.x=r.y=r.z=r.w=x; return r; }

__device__ __forceinline__ float fetch_mov(const float* __restrict__ m, int d, int h, int w) {
    if ((unsigned)d >= (unsigned)D_ || (unsigned)h >= (unsigned)H_ || (unsigned)w >= (unsigned)W_) return 0.0f;
    return m[(size_t)(d*H_ + h)*W_ + w];
}

__device__ __forceinline__ float trilerp(const float* __restrict__ mov,
                                         float cd, float ch, float cw) {
    float fd = floorf(cd), fh = floorf(ch), fw = floorf(cw);
    int di = (int)fd, hi = (int)fh, wi = (int)fw;
    float td = cd - fd, th = ch - fh, tw = cw - fw;
    float c000, c001, c010, c011, c100, c101, c110, c111;
    if (di >= 0 && di < D_-1 && hi >= 0 && hi < H_-1 && wi >= 0 && wi < W_-1) {
        const float* p = mov + (size_t)di*HW + hi*W_ + wi;
        c000 = p[0];    c001 = p[1];
        c010 = p[W_];   c011 = p[W_+1];
        const float* q = p + HW;
        c100 = q[0];    c101 = q[1];
        c110 = q[W_];   c111 = q[W_+1];
    } else {
        c000 = fetch_mov(mov, di,   hi,   wi  );
        c001 = fetch_mov(mov, di,   hi,   wi+1);
        c010 = fetch_mov(mov, di,   hi+1, wi  );
        c011 = fetch_mov(mov, di,   hi+1, wi+1);
        c100 = fetch_mov(mov, di+1, hi,   wi  );
        c101 = fetch_mov(mov, di+1, hi,   wi+1);
        c110 = fetch_mov(mov, di+1, hi+1, wi  );
        c111 = fetch_mov(mov, di+1, hi+1, wi+1);
    }
    float c00 = c000 + tw*(c001 - c000);
    float c01 = c010 + tw*(c011 - c010);
    float c10 = c100 + tw*(c101 - c100);
    float c11 = c110 + tw*(c111 - c110);
    float c0 = c00 + th*(c01 - c00);
    float c1 = c10 + th*(c11 - c10);
    return c0 + td*(c1 - c0);
}

// ---------------------------------------------------------------------------
// v4 force_wh (UNCHANGED from the 582 µs run): phase A restructured to starve
// the VMEM path.
//   A0: stage warped/fix center-plane tiles [38][48] in LDS, CLAMP-filled
//       (clamp-fill == the edge substitute rule).
//   A1: h/w taps from LDS; 7 unconditional coalesced global b128 loads
//       (d+-1 via clamped-plane offsets + 3 vf).
//   Phases B/C/D: swizzled u overlay (verified v3).
// ---------------------------------------------------------------------------
#define UROW 48   // 12 f4 per row (10 used + swizzle domain padding)

__global__ __launch_bounds__(256, 4) void force_wh_kernel(const float* __restrict__ warped,
                                                          const float* __restrict__ fix,
                                                          const float* __restrict__ vf,
                                                          float* __restrict__ tout,
                                                          int zero_vf) {
    __shared__ float u[3][36][UROW];  // phase A1 out; phase C/D: s1 overlay
    __shared__ float tw[38][48];      // warped[d] tile, rows h0-3..h0+34, cols w0-8..w0+39 (clamped)
    __shared__ float tf[38][48];      // fix[d] tile, same footprint
    const int tx = threadIdx.x;       // 0..7
    const int ty = threadIdx.y;       // 0..31
    const int tid = ty*8 + tx;
    const int bswz = (blockIdx.x & 7)*400 + (blockIdx.x >> 3);
    const int d   = bswz / 25;
    const int rem = bswz % 25;
    const int h0 = (rem / 5) * 32;
    const int w0 = (rem % 5) * 32;

    // swizzled f4 accessor: logical f4-col fc of row r lives at fc ^ (r&3)
    #define UF4(ch, r, fc) (((float4*)&u[(ch)][(r)][0]) + ((fc) ^ ((r)&3)))

    // ---- phase A0: stage warped/fix center-plane tiles, clamp-filled.
    for (int s = tid; s < 456; s += 256) {
        int R  = s / 12, C4 = s % 12;
        int gh = h0 - 3 + R;
        int ghc = gh < 0 ? 0 : (gh > H_-1 ? H_-1 : gh);
        int gw = w0 - 8 + 4*C4;
        size_t rb = (size_t)d*HW + (size_t)ghc*W_;
        float4 wv, fv;
        if (gw < 0) {
            wv = bcast4(warped[rb]);  fv = bcast4(fix[rb]);
        } else if (gw + 4 > W_) {
            wv = bcast4(warped[rb + W_-1]); fv = bcast4(fix[rb + W_-1]);
        } else {
            wv = *(const float4*)(warped + rb + gw);
            fv = *(const float4*)(fix    + rb + gw);
        }
        *(float4*)&tw[R][4*C4] = wv;
        *(float4*)&tf[R][4*C4] = fv;
    }
    __syncthreads();

    // ---- phase A1: demons force from LDS taps + 7 batched global loads.
    for (int slot = tid; slot < 360; slot += 256) {
        int r = slot/10, c = slot%10;
        int gh = h0 - 2 + r;
        int gw = w0 - 4 + 4*c;
        F4 o0, o1, o2;
        if ((unsigned)gh < (unsigned)H_ && gw >= 0 && gw + 4 <= W_) {
            size_t base = (size_t)d*HW + (size_t)gh*W_ + gw;
            int i4 = (int)(base >> 2);
            int up = (d < D_-1) ?  (HW/4) : 0;
            int dn = (d > 0)    ? -(HW/4) : 0;
            const float4* w4p = (const float4*)warped;
            const float4* f4p = (const float4*)fix;
            F4 du, dnv, fdu, fdn;
            du.v  = w4p[i4 + up];
            dnv.v = w4p[i4 + dn];
            fdu.v = f4p[i4 + up];
            fdn.v = f4p[i4 + dn];
            if (zero_vf) {
                o0.v = zero4(); o1.v = zero4(); o2.v = zero4();
            } else {
                o0.v = ((const float4*)vf)[i4];
                o1.v = ((const float4*)vf)[i4 + N4];
                o2.v = ((const float4*)vf)[i4 + 2*N4];
            }
            int sr = r + 1, sc = 4*c + 4;
            F4 cc, fc, hu, hd, fhu, fhd;
            cc.v  = *(const float4*)&tw[sr  ][sc];
            fc.v  = *(const float4*)&tf[sr  ][sc];
            hu.v  = *(const float4*)&tw[sr+1][sc];
            hd.v  = *(const float4*)&tw[sr-1][sc];
            fhu.v = *(const float4*)&tf[sr+1][sc];
            fhd.v = *(const float4*)&tf[sr-1][sc];
            float cl = tw[sr][sc-1], cr = tw[sr][sc+4];
            float fl = tf[sr][sc-1], fr = tf[sr][sc+4];
            float hs  = (gh==0 || gh==H_-1) ? 1.f : 0.5f;
            float dsc = (d==0  || d==D_-1)  ? 1.f : 0.5f;
            float m [6] = {cl, cc.a[0], cc.a[1], cc.a[2], cc.a[3], cr};
            float fm[6] = {fl, fc.a[0], fc.a[1], fc.a[2], fc.a[3], fr};
            #pragma unroll
            for (int j = 0; j < 4; ++j) {
                int wj = gw + j;
                float wsc  = (wj == 0 || wj == W_-1) ? 1.f : 0.5f;
                float prev  = (wj == 0)    ? m[1]  : m[j];
                float next  = (wj == W_-1) ? m[4]  : m[j+2];
                float fprev = (wj == 0)    ? fm[1] : fm[j];
                float fnext = (wj == W_-1) ? fm[4] : fm[j+2];
                float G0 = dsc*(du.a[j] - dnv.a[j]) + dsc*(fdu.a[j] - fdn.a[j]);
                float G1 = hs *(hu.a[j] - hd.a[j])  + hs *(fhu.a[j] - fhd.a[j]);
                float G2 = wsc*(next - prev)        + wsc*(fnext - fprev);
                float diff = cc.a[j] - fc.a[j];
                float denom = G0*G0 + G1*G1 + G2*G2 + diff*diff;
                float scale = (denom > 1e-6f) ? (-diff/denom) : 0.0f;
                o0.a[j] += scale*G0;
                o1.a[j] += scale*G1;
                o2.a[j] += scale*G2;
            }
        } else {
            o0.v = zero4(); o1.v = zero4(); o2.v = zero4();
        }
        *UF4(0, r, c) = o0.v;
        *UF4(1, r, c) = o1.v;
        *UF4(2, r, c) = o2.v;
    }
    __syncthreads();

    // ---- phase B: W-conv into registers. 216 jobs = 3ch x 36 rows x 2 halves.
    F4 wout[4];
    int jch = 0, jr = 0, jh = 0;
    const bool has = (tid < 216);
    if (has) {
        jch = tid / 72;
        int rem2 = tid % 72;
        jr = rem2 >> 1;
        jh = rem2 & 1;
        F4 q[6];
        #pragma unroll
        for (int i = 0; i < 6; ++i) q[i].v = *UF4(jch, jr, 4*jh + i);
        float mm[24];
        #pragma unroll
        for (int i = 0; i < 6; ++i) {
            mm[4*i+0]=q[i].a[0]; mm[4*i+1]=q[i].a[1]; mm[4*i+2]=q[i].a[2]; mm[4*i+3]=q[i].a[3];
        }
        #pragma unroll
        for (int o = 0; o < 16; ++o)
            wout[o>>2].a[o&3] = K2*(mm[o+2]+mm[o+6]) + K1*(mm[o+3]+mm[o+5]) + K0*mm[o+4];
    }
    __syncthreads();

    // ---- phase C: write s1 overlay back into u
    if (has) {
        #pragma unroll
        for (int f = 0; f < 4; ++f) *UF4(jch, jr, 4*jh + f) = wout[f].v;
    }
    __syncthreads();

    // ---- phase D: H-conv from overlay + store
    size_t base = (size_t)d*HW + (h0+ty)*W_ + w0 + 4*tx;
    #pragma unroll
    for (int ch = 0; ch < 3; ++ch) {
        F4 q0, q1, q2, q3, q4;
        q0.v = *UF4(ch, ty  , tx);
        q1.v = *UF4(ch, ty+1, tx);
        q2.v = *UF4(ch, ty+2, tx);
        q3.v = *UF4(ch, ty+3, tx);
        q4.v = *UF4(ch, ty+4, tx);
        float4 s2;
        s2.x = K2*(q0.a[0]+q4.a[0]) + K1*(q1.a[0]+q3.a[0]) + K0*q2.a[0];
        s2.y = K2*(q0.a[1]+q4.a[1]) + K1*(q1.a[1]+q3.a[1]) + K0*q2.a[1];
        s2.z = K2*(q0.a[2]+q4.a[2]) + K1*(q1.a[2]+q3.a[2]) + K0*q2.a[2];
        s2.w = K2*(q0.a[3]+q4.a[3]) + K1*(q1.a[3]+q3.a[3]) + K0*q2.a[3];
        *(float4*)(tout + (size_t)ch*NVOX + base) = s2;
    }
    #undef UF4
}

// ---------------------------------------------------------------------------
// v5 smooth_d_warp: d-column marching, kd=4. Each thread owns 4 consecutive
// d-planes at one (h,w) f4 and keeps tbuf tap planes in a statically-indexed
// register window: tap loads per 4 outputs drop 60 -> 24 (-60%), total VMEM
// instr -26%. Two half-passes (6-plane window, static shift) keep the live
// set ~18 F4 so no scratch. Grid 800 blocks; XCD-swizzle gives XCD k the
// same contiguous 16-plane d-slab as force_wh.
// ---------------------------------------------------------------------------
__global__ __launch_bounds__(256) void smooth_d_warp_kernel(const float* __restrict__ t,
                                                            const float* __restrict__ mov,
                                                            float* __restrict__ vf_out,
                                                            float* __restrict__ warped_out,
                                                            int do_warp) {
    const int chunk = (blockIdx.x & 7)*100 + (blockIdx.x >> 3);   // 800 = 8*100
    const int col = chunk*256 + (int)threadIdx.x;                 // [0, N4/4)
    const int hw4 = col % HW4;
    const int d0  = (col / HW4) * 4;
    const int w = (hw4 % (W_/4)) * 4;
    const int h = hw4 / (W_/4);

    F4 q[3][6];   // window: q[ch][i] = tbuf tap at plane (pbase + i), zero outside
    // ---- pass 1: planes d0-2 .. d0+3, outputs k=0,1
    #pragma unroll
    for (int ch = 0; ch < 3; ++ch) {
        const float4* tp = (const float4*)(t + (size_t)ch*NVOX);
        #pragma unroll
        for (int i = 0; i < 6; ++i) {
            int p = d0 - 2 + i;
            q[ch][i].v = ((unsigned)p < (unsigned)D_) ? tp[p*HW4 + hw4] : zero4();
        }
    }
    #pragma unroll
    for (int k = 0; k < 2; ++k) {
        F4 va[3];
        #pragma unroll
        for (int ch = 0; ch < 3; ++ch) {
            #pragma unroll
            for (int j = 0; j < 4; ++j)
                va[ch].a[j] = K2*(q[ch][k].a[j]+q[ch][k+4].a[j])
                            + K1*(q[ch][k+1].a[j]+q[ch][k+3].a[j])
                            + K0*q[ch][k+2].a[j];
        }
        int i4 = (d0+k)*HW4 + hw4;
        ((float4*)vf_out)[i4]        = va[0].v;
        ((float4*)vf_out)[i4 + N4]   = va[1].v;
        ((float4*)vf_out)[i4 + 2*N4] = va[2].v;
        if (do_warp) {
            F4 r4o;
            #pragma unroll
            for (int j = 0; j < 4; ++j) {
                float cd = (float)(d0+k) + va[0].a[j];
                float ch2 = (float)h      + va[1].a[j];
                float cw = (float)(w + j) + va[2].a[j];
                r4o.a[j] = trilerp(mov, cd, ch2, cw);
            }
            ((float4*)warped_out)[i4] = r4o.v;
        }
    }
    // ---- shift window by 2: planes d0 .. d0+5, outputs k=2,3
    #pragma unroll
    for (int ch = 0; ch < 3; ++ch) {
        const float4* tp = (const float4*)(t + (size_t)ch*NVOX);
        #pragma unroll
        for (int i = 0; i < 4; ++i) q[ch][i] = q[ch][i+2];
        #pragma unroll
        for (int i = 4; i < 6; ++i) {
            int p = d0 + i;
            q[ch][i].v = ((unsigned)p < (unsigned)D_) ? tp[p*HW4 + hw4] : zero4();
        }
    }
    #pragma unroll
    for (int k = 2; k < 4; ++k) {
        F4 va[3];
        #pragma unroll
        for (int ch = 0; ch < 3; ++ch) {
            #pragma unroll
            for (int j = 0; j < 4; ++j)
                va[ch].a[j] = K2*(q[ch][k-2].a[j]+q[ch][k+2].a[j])
                            + K1*(q[ch][k-1].a[j]+q[ch][k+1].a[j])
                            + K0*q[ch][k].a[j];
        }
        int i4 = (d0+k)*HW4 + hw4;
        ((float4*)vf_out)[i4]        = va[0].v;
        ((float4*)vf_out)[i4 + N4]   = va[1].v;
        ((float4*)vf_out)[i4 + 2*N4] = va[2].v;
        if (do_warp) {
            F4 r4o;
            #pragma unroll
            for (int j = 0; j < 4; ++j) {
                float cd = (float)(d0+k) + va[0].a[j];
                float ch2 = (float)h      + va[1].a[j];
                float cw = (float)(w + j) + va[2].a[j];
                r4o.a[j] = trilerp(mov, cd, ch2, cw);
            }
            ((float4*)warped_out)[i4] = r4o.v;
        }
    }
}

extern "C" void kernel_launch(void* const* d_in, const int* in_sizes, int n_in,
                              void* d_out, int out_size, void* d_ws, size_t ws_size,
                              hipStream_t stream) {
    const float* mov = (const float*)d_in[0];
    const float* fix = (const float*)d_in[1];
    const int ITERS = 10;

    float* ws     = (float*)d_ws;
    float* vfA    = ws;                       // 3N — the vf state
    float* tbuf   = ws + (size_t)3*NVOX;      // 3N — WH-smoothed field
    float* warped = ws + (size_t)6*NVOX;      // N

    for (int it = 0; it < ITERS; ++it) {
        // it==0: vf == 0 => warped == mov exactly (integer-coordinate trilerp)
        const float* wsrc = (it == 0) ? mov : warped;
        force_wh_kernel<<<dim3(3200), dim3(8,32), 0, stream>>>(wsrc, fix, vfA, tbuf,
                                                               it == 0 ? 1 : 0);
        float* vdst = (it == ITERS-1) ? (float*)d_out : vfA;
        smooth_d_warp_kernel<<<dim3(800), dim3(256), 0, stream>>>(tbuf, mov, vdst, warped,
                                                                  it == ITERS-1 ? 0 : 1);
    }
}

// Round 6
// 566.665 us; speedup vs baseline: 1.1389x; 1.1389x over previous
//
#include <hip/hip_runtime.h>
#include <math.h>

#define D_ 128
#define H_ 160
#define W_ 160
#define NVOX (D_*H_*W_)
#define HW (H_*W_)
#define N4 (NVOX/4)
#define HW4 (HW/4)

// Gaussian kernel, sigma=1, radius=2, normalized
#define K0 0.40261996f
#define K1 0.24420134f
#define K2 0.05448868f

union F4 { float4 v; float a[4]; };

__device__ __forceinline__ float4 zero4() { float4 z; z.x=z.y=z.z=z.w=0.f; return z; }
__device__ __forceinline__ float4 bcast4(float x) { float4 r; r.x=r.y=r.z=r.w=x; return r; }

__device__ __forceinline__ float fetch_mov(const float* __restrict__ m, int d, int h, int w) {
    if ((unsigned)d >= (unsigned)D_ || (unsigned)h >= (unsigned)H_ || (unsigned)w >= (unsigned)W_) return 0.0f;
    return m[(size_t)(d*H_ + h)*W_ + w];
}

__device__ __forceinline__ float trilerp(const float* __restrict__ mov,
                                         float cd, float ch, float cw) {
    float fd = floorf(cd), fh = floorf(ch), fw = floorf(cw);
    int di = (int)fd, hi = (int)fh, wi = (int)fw;
    float td = cd - fd, th = ch - fh, tw = cw - fw;
    float c000, c001, c010, c011, c100, c101, c110, c111;
    if (di >= 0 && di < D_-1 && hi >= 0 && hi < H_-1 && wi >= 0 && wi < W_-1) {
        const float* p = mov + (size_t)di*HW + hi*W_ + wi;
        c000 = p[0];    c001 = p[1];
        c010 = p[W_];   c011 = p[W_+1];
        const float* q = p + HW;
        c100 = q[0];    c101 = q[1];
        c110 = q[W_];   c111 = q[W_+1];
    } else {
        c000 = fetch_mov(mov, di,   hi,   wi  );
        c001 = fetch_mov(mov, di,   hi,   wi+1);
        c010 = fetch_mov(mov, di,   hi+1, wi  );
        c011 = fetch_mov(mov, di,   hi+1, wi+1);
        c100 = fetch_mov(mov, di+1, hi,   wi  );
        c101 = fetch_mov(mov, di+1, hi,   wi+1);
        c110 = fetch_mov(mov, di+1, hi+1, wi  );
        c111 = fetch_mov(mov, di+1, hi+1, wi+1);
    }
    float c00 = c000 + tw*(c001 - c000);
    float c01 = c010 + tw*(c011 - c010);
    float c10 = c100 + tw*(c101 - c100);
    float c11 = c110 + tw*(c111 - c110);
    float c0 = c00 + th*(c01 - c00);
    float c1 = c10 + th*(c11 - c10);
    return c0 + td*(c1 - c0);
}

// ---------------------------------------------------------------------------
// v4 force_wh (UNCHANGED from the 582 µs run): phase A restructured to starve
// the VMEM path.
//   A0: stage warped/fix center-plane tiles [38][48] in LDS, CLAMP-filled
//       (clamp-fill == the edge substitute rule).
//   A1: h/w taps from LDS; 7 unconditional coalesced global b128 loads
//       (d+-1 via clamped-plane offsets + 3 vf).
//   Phases B/C/D: swizzled u overlay (verified v3).
// ---------------------------------------------------------------------------
#define UROW 48   // 12 f4 per row (10 used + swizzle domain padding)

__global__ __launch_bounds__(256, 4) void force_wh_kernel(const float* __restrict__ warped,
                                                          const float* __restrict__ fix,
                                                          const float* __restrict__ vf,
                                                          float* __restrict__ tout,
                                                          int zero_vf) {
    __shared__ float u[3][36][UROW];  // phase A1 out; phase C/D: s1 overlay
    __shared__ float tw[38][48];      // warped[d] tile, rows h0-3..h0+34, cols w0-8..w0+39 (clamped)
    __shared__ float tf[38][48];      // fix[d] tile, same footprint
    const int tx = threadIdx.x;       // 0..7
    const int ty = threadIdx.y;       // 0..31
    const int tid = ty*8 + tx;
    const int bswz = (blockIdx.x & 7)*400 + (blockIdx.x >> 3);
    const int d   = bswz / 25;
    const int rem = bswz % 25;
    const int h0 = (rem / 5) * 32;
    const int w0 = (rem % 5) * 32;

    // swizzled f4 accessor: logical f4-col fc of row r lives at fc ^ (r&3)
    #define UF4(ch, r, fc) (((float4*)&u[(ch)][(r)][0]) + ((fc) ^ ((r)&3)))

    // ---- phase A0: stage warped/fix center-plane tiles, clamp-filled.
    for (int s = tid; s < 456; s += 256) {
        int R  = s / 12, C4 = s % 12;
        int gh = h0 - 3 + R;
        int ghc = gh < 0 ? 0 : (gh > H_-1 ? H_-1 : gh);
        int gw = w0 - 8 + 4*C4;
        size_t rb = (size_t)d*HW + (size_t)ghc*W_;
        float4 wv, fv;
        if (gw < 0) {
            wv = bcast4(warped[rb]);  fv = bcast4(fix[rb]);
        } else if (gw + 4 > W_) {
            wv = bcast4(warped[rb + W_-1]); fv = bcast4(fix[rb + W_-1]);
        } else {
            wv = *(const float4*)(warped + rb + gw);
            fv = *(const float4*)(fix    + rb + gw);
        }
        *(float4*)&tw[R][4*C4] = wv;
        *(float4*)&tf[R][4*C4] = fv;
    }
    __syncthreads();

    // ---- phase A1: demons force from LDS taps + 7 batched global loads.
    for (int slot = tid; slot < 360; slot += 256) {
        int r = slot/10, c = slot%10;
        int gh = h0 - 2 + r;
        int gw = w0 - 4 + 4*c;
        F4 o0, o1, o2;
        if ((unsigned)gh < (unsigned)H_ && gw >= 0 && gw + 4 <= W_) {
            size_t base = (size_t)d*HW + (size_t)gh*W_ + gw;
            int i4 = (int)(base >> 2);
            int up = (d < D_-1) ?  (HW/4) : 0;
            int dn = (d > 0)    ? -(HW/4) : 0;
            const float4* w4p = (const float4*)warped;
            const float4* f4p = (const float4*)fix;
            F4 du, dnv, fdu, fdn;
            du.v  = w4p[i4 + up];
            dnv.v = w4p[i4 + dn];
            fdu.v = f4p[i4 + up];
            fdn.v = f4p[i4 + dn];
            if (zero_vf) {
                o0.v = zero4(); o1.v = zero4(); o2.v = zero4();
            } else {
                o0.v = ((const float4*)vf)[i4];
                o1.v = ((const float4*)vf)[i4 + N4];
                o2.v = ((const float4*)vf)[i4 + 2*N4];
            }
            int sr = r + 1, sc = 4*c + 4;
            F4 cc, fc, hu, hd, fhu, fhd;
            cc.v  = *(const float4*)&tw[sr  ][sc];
            fc.v  = *(const float4*)&tf[sr  ][sc];
            hu.v  = *(const float4*)&tw[sr+1][sc];
            hd.v  = *(const float4*)&tw[sr-1][sc];
            fhu.v = *(const float4*)&tf[sr+1][sc];
            fhd.v = *(const float4*)&tf[sr-1][sc];
            float cl = tw[sr][sc-1], cr = tw[sr][sc+4];
            float fl = tf[sr][sc-1], fr = tf[sr][sc+4];
            float hs  = (gh==0 || gh==H_-1) ? 1.f : 0.5f;
            float dsc = (d==0  || d==D_-1)  ? 1.f : 0.5f;
            float m [6] = {cl, cc.a[0], cc.a[1], cc.a[2], cc.a[3], cr};
            float fm[6] = {fl, fc.a[0], fc.a[1], fc.a[2], fc.a[3], fr};
            #pragma unroll
            for (int j = 0; j < 4; ++j) {
                int wj = gw + j;
                float wsc  = (wj == 0 || wj == W_-1) ? 1.f : 0.5f;
                float prev  = (wj == 0)    ? m[1]  : m[j];
                float next  = (wj == W_-1) ? m[4]  : m[j+2];
                float fprev = (wj == 0)    ? fm[1] : fm[j];
                float fnext = (wj == W_-1) ? fm[4] : fm[j+2];
                float G0 = dsc*(du.a[j] - dnv.a[j]) + dsc*(fdu.a[j] - fdn.a[j]);
                float G1 = hs *(hu.a[j] - hd.a[j])  + hs *(fhu.a[j] - fhd.a[j]);
                float G2 = wsc*(next - prev)        + wsc*(fnext - fprev);
                float diff = cc.a[j] - fc.a[j];
                float denom = G0*G0 + G1*G1 + G2*G2 + diff*diff;
                float scale = (denom > 1e-6f) ? (-diff/denom) : 0.0f;
                o0.a[j] += scale*G0;
                o1.a[j] += scale*G1;
                o2.a[j] += scale*G2;
            }
        } else {
            o0.v = zero4(); o1.v = zero4(); o2.v = zero4();
        }
        *UF4(0, r, c) = o0.v;
        *UF4(1, r, c) = o1.v;
        *UF4(2, r, c) = o2.v;
    }
    __syncthreads();

    // ---- phase B: W-conv into registers. 216 jobs = 3ch x 36 rows x 2 halves.
    F4 wout[4];
    int jch = 0, jr = 0, jh = 0;
    const bool has = (tid < 216);
    if (has) {
        jch = tid / 72;
        int rem2 = tid % 72;
        jr = rem2 >> 1;
        jh = rem2 & 1;
        F4 q[6];
        #pragma unroll
        for (int i = 0; i < 6; ++i) q[i].v = *UF4(jch, jr, 4*jh + i);
        float mm[24];
        #pragma unroll
        for (int i = 0; i < 6; ++i) {
            mm[4*i+0]=q[i].a[0]; mm[4*i+1]=q[i].a[1]; mm[4*i+2]=q[i].a[2]; mm[4*i+3]=q[i].a[3];
        }
        #pragma unroll
        for (int o = 0; o < 16; ++o)
            wout[o>>2].a[o&3] = K2*(mm[o+2]+mm[o+6]) + K1*(mm[o+3]+mm[o+5]) + K0*mm[o+4];
    }
    __syncthreads();

    // ---- phase C: write s1 overlay back into u
    if (has) {
        #pragma unroll
        for (int f = 0; f < 4; ++f) *UF4(jch, jr, 4*jh + f) = wout[f].v;
    }
    __syncthreads();

    // ---- phase D: H-conv from overlay + store
    size_t base = (size_t)d*HW + (h0+ty)*W_ + w0 + 4*tx;
    #pragma unroll
    for (int ch = 0; ch < 3; ++ch) {
        F4 q0, q1, q2, q3, q4;
        q0.v = *UF4(ch, ty  , tx);
        q1.v = *UF4(ch, ty+1, tx);
        q2.v = *UF4(ch, ty+2, tx);
        q3.v = *UF4(ch, ty+3, tx);
        q4.v = *UF4(ch, ty+4, tx);
        float4 s2;
        s2.x = K2*(q0.a[0]+q4.a[0]) + K1*(q1.a[0]+q3.a[0]) + K0*q2.a[0];
        s2.y = K2*(q0.a[1]+q4.a[1]) + K1*(q1.a[1]+q3.a[1]) + K0*q2.a[1];
        s2.z = K2*(q0.a[2]+q4.a[2]) + K1*(q1.a[2]+q3.a[2]) + K0*q2.a[2];
        s2.w = K2*(q0.a[3]+q4.a[3]) + K1*(q1.a[3]+q3.a[3]) + K0*q2.a[3];
        *(float4*)(tout + (size_t)ch*NVOX + base) = s2;
    }
    #undef UF4
}

// ---------------------------------------------------------------------------
// v6 smooth_d_warp: d-quad blocks with LDS tap sharing — reduces VMEM
// instructions at CONSTANT thread count (v5's confound removed; v5's
// 4x-fewer-threads variant regressed => concurrency matters).
// Block = 256 threads = 64 hw4-lanes x 4 d-lanes, covering 4 d-planes x
// 64 f4. The 8 tbuf tap planes x 3ch the block needs are staged into LDS
// cooperatively: 6 coalesced b128 loads/thread (waves load whole 1KB
// plane-rows), then 15 taps read from LDS (wave-uniform row, lane-stride-1,
// conflict-free). Per-thread VMEM 51 -> 42. Zero-fill outside [0,D) = the
// D-conv's zero padding. Grid 3200, XCD-swizzled so XCD k owns d in
// [16k,16k+16) — same slab as force_wh.
// ---------------------------------------------------------------------------
__global__ __launch_bounds__(256) void smooth_d_warp_kernel(const float* __restrict__ t,
                                                            const float* __restrict__ mov,
                                                            float* __restrict__ vf_out,
                                                            float* __restrict__ warped_out,
                                                            int do_warp) {
    __shared__ float4 sm[24][64];     // [ch*8 + r][hw4-lane], planes d0-2 .. d0+5
    const int chunk = (blockIdx.x & 7)*400 + (blockIdx.x >> 3);
    const int db = chunk / 100;       // d-tile: planes db*4 .. db*4+3
    const int hb = chunk % 100;       // hw-tile: f4 indices hb*64 .. hb*64+63
    const int tdx = threadIdx.x & 63; // hw4 lane
    const int tdz = threadIdx.x >> 6; // d lane 0..3
    const int d0 = db*4;
    const int hw4 = hb*64 + tdx;

    // ---- stage 8 planes x 3 ch: 24 plane-rows, wave w loads rows w*6..w*6+5
    #pragma unroll
    for (int i = 0; i < 6; ++i) {
        int pc = tdz*6 + i;           // 0..23
        int ch = pc >> 3;             // pc/8
        int r  = pc & 7;              // plane row
        int p  = d0 - 2 + r;
        const float4* tp = (const float4*)(t + (size_t)ch*NVOX);
        sm[pc][tdx] = ((unsigned)p < (unsigned)D_) ? tp[p*HW4 + hw4] : zero4();
    }
    __syncthreads();

    // ---- D-conv from LDS + warp. Output (d0+tdz, hw4): taps rows tdz..tdz+4.
    const int d = d0 + tdz;
    const int w = (hw4 % (W_/4)) * 4;
    const int h = hw4 / (W_/4);
    F4 va[3];
    #pragma unroll
    for (int ch = 0; ch < 3; ++ch) {
        F4 q0, q1, q2, q3, q4;
        q0.v = sm[ch*8 + tdz    ][tdx];
        q1.v = sm[ch*8 + tdz + 1][tdx];
        q2.v = sm[ch*8 + tdz + 2][tdx];
        q3.v = sm[ch*8 + tdz + 3][tdx];
        q4.v = sm[ch*8 + tdz + 4][tdx];
        va[ch].a[0] = K2*(q0.a[0]+q4.a[0]) + K1*(q1.a[0]+q3.a[0]) + K0*q2.a[0];
        va[ch].a[1] = K2*(q0.a[1]+q4.a[1]) + K1*(q1.a[1]+q3.a[1]) + K0*q2.a[1];
        va[ch].a[2] = K2*(q0.a[2]+q4.a[2]) + K1*(q1.a[2]+q3.a[2]) + K0*q2.a[2];
        va[ch].a[3] = K2*(q0.a[3]+q4.a[3]) + K1*(q1.a[3]+q3.a[3]) + K0*q2.a[3];
    }
    const int i4 = d*HW4 + hw4;
    ((float4*)vf_out)[i4]        = va[0].v;
    ((float4*)vf_out)[i4 + N4]   = va[1].v;
    ((float4*)vf_out)[i4 + 2*N4] = va[2].v;
    if (do_warp) {
        F4 r4o;
        #pragma unroll
        for (int j = 0; j < 4; ++j) {
            float cd  = (float)d       + va[0].a[j];
            float ch2 = (float)h       + va[1].a[j];
            float cw  = (float)(w + j) + va[2].a[j];
            r4o.a[j] = trilerp(mov, cd, ch2, cw);
        }
        ((float4*)warped_out)[i4] = r4o.v;
    }
}

extern "C" void kernel_launch(void* const* d_in, const int* in_sizes, int n_in,
                              void* d_out, int out_size, void* d_ws, size_t ws_size,
                              hipStream_t stream) {
    const float* mov = (const float*)d_in[0];
    const float* fix = (const float*)d_in[1];
    const int ITERS = 10;

    float* ws     = (float*)d_ws;
    float* vfA    = ws;                       // 3N — the vf state
    float* tbuf   = ws + (size_t)3*NVOX;      // 3N — WH-smoothed field
    float* warped = ws + (size_t)6*NVOX;      // N

    for (int it = 0; it < ITERS; ++it) {
        // it==0: vf == 0 => warped == mov exactly (integer-coordinate trilerp)
        const float* wsrc = (it == 0) ? mov : warped;
        force_wh_kernel<<<dim3(3200), dim3(8,32), 0, stream>>>(wsrc, fix, vfA, tbuf,
                                                               it == 0 ? 1 : 0);
        float* vdst = (it == ITERS-1) ? (float*)d_out : vfA;
        smooth_d_warp_kernel<<<dim3(3200), dim3(256), 0, stream>>>(tbuf, mov, vdst, warped,
                                                                   it == ITERS-1 ? 0 : 1);
    }
}